// Round 6
// baseline (533.499 us; speedup 1.0000x reference)
//
#include <hip/hip_runtime.h>

#define NN 50000
#define NE 800000

__device__ __forceinline__ float sigm(float v) { return 1.0f / (1.0f + __expf(-v)); }

// ===========================================================================
// Shared helpers (both paths)
// ===========================================================================

// Exclusive scan of cnt[NN] -> offset[NN+1]. Single block, 256 threads.
__global__ void scan_offsets(const int* __restrict__ cnt_i,
                             int* __restrict__ offset)
{
    __shared__ int sums[257];
    int t = threadIdx.x;
    int lo = t * 196, hi = min(lo + 196, NN);
    int s = 0;
    for (int i = lo; i < hi; ++i) s += cnt_i[i];
    sums[t] = s;
    __syncthreads();
    if (t == 0) {
        int run = 0;
        for (int i = 0; i < 256; ++i) { int v = sums[i]; sums[i] = run; run += v; }
        sums[256] = run;
    }
    __syncthreads();
    int run = sums[t];
    for (int i = lo; i < hi; ++i) { offset[i] = run; run += cnt_i[i]; }
    if (t == 255) offset[NN] = sums[256];
}

// Gather: 16-lane group per node sums its contiguous msg rows (coalesced,
// no atomics), then fused node update (+ output MLP when FINAL).
template<int DIN, bool FINAL>
__global__ __launch_bounds__(256) void gather_nodes(
        const float* __restrict__ xin,    // [NN][DIN]
        const float* __restrict__ root,   // [DIN][16]
        const float* __restrict__ bias,   // [16]
        const int*   __restrict__ offset, // [NN+1] (dst CSR)
        const float* __restrict__ msgbuf, // [NE][16]
        const float* __restrict__ mW1,    // [16][16] (FINAL)
        const float* __restrict__ mb1,    // [16]
        const float* __restrict__ mW2,    // [16]
        const float* __restrict__ mb2,    // [1]
        float* __restrict__ xout)         // [NN][16] or [NN]
{
    __shared__ __align__(16) float rootL[DIN * 16];
    __shared__ __align__(16) float biasL[16];
    __shared__ __align__(16) float w1m[256];
    __shared__ __align__(16) float b1m[16];
    __shared__ __align__(16) float w2m[16];
    __shared__ float b2m;
    int tid = threadIdx.x;
    for (int i = tid; i < DIN * 16; i += 256) rootL[i] = root[i];
    if (tid < 16) biasL[tid] = bias[tid];
    if constexpr (FINAL) {
        w1m[tid] = mW1[tid];
        if (tid < 16) { b1m[tid] = mb1[tid]; w2m[tid] = mW2[tid]; }
        if (tid == 0) b2m = mb2[0];
    }
    __syncthreads();

    int ch = tid & 15;
    int n  = blockIdx.x * 16 + (tid >> 4);   // NN == 3125*16 exactly
    int s  = offset[n];
    int epos = offset[n + 1];
    int deg = epos - s;

    float acc = 0.f;
    for (int j = s; j < epos; ++j)
        acc += msgbuf[(size_t)j * 16 + ch];

    float v = acc / fmaxf((float)deg, 1.0f) + biasL[ch];
#pragma unroll
    for (int i = 0; i < DIN; ++i)
        v += xin[(size_t)n * DIN + i] * rootL[i * 16 + ch];
    v = fmaxf(v, 0.f);

    if constexpr (!FINAL) {
        xout[(size_t)n * 16 + ch] = v;
    } else {
        float z = b1m[ch];
#pragma unroll
        for (int o = 0; o < 16; ++o) {
            float vo = __shfl(v, o, 16);
            z += vo * w1m[o * 16 + ch];
        }
        float ss = z * sigm(z) * w2m[ch];
#pragma unroll
        for (int off = 8; off; off >>= 1) ss += __shfl_xor(ss, off, 16);
        if (ch == 0) xout[n] = sigm(ss + b2m);
    }
}

// ===========================================================================
// NEW PATH: src-sorted G-factorized pipeline
// ===========================================================================

// ranks within src and dst buckets (int atomics only; graph static -> once).
__global__ void build_ranks(const int* __restrict__ ei,
                            int* __restrict__ cnt_s, int* __restrict__ cnt_d,
                            int* __restrict__ rank_s, int* __restrict__ rank_d)
{
    int e = blockIdx.x * 256 + threadIdx.x;   // NE == 3125*256 exactly
    int s = ei[e], d = ei[NE + e];
    rank_s[e] = atomicAdd(cnt_s + s, 1);
    rank_d[e] = atomicAdd(cnt_d + d, 1);
}

// materialize src-sorted order: srcid/dstpos/ea_s at pos = off_s[src]+rank_s.
__global__ void build_perm(const int* __restrict__ ei,
                           const float* __restrict__ ea,
                           const int* __restrict__ off_s, const int* __restrict__ off_d,
                           const int* __restrict__ rank_s, const int* __restrict__ rank_d,
                           int* __restrict__ srcid, int* __restrict__ dstpos,
                           float* __restrict__ ea_s)
{
    int e = blockIdx.x * 256 + threadIdx.x;
    int s = ei[e], d = ei[NE + e];
    int pos = off_s[s] + rank_s[e];
    srcid[pos]  = s;
    dstpos[pos] = off_d[d] + rank_d[e];
    ((float4*)ea_s)[pos] = ((const float4*)ea)[e];
}

// Per-node: G[(k*4+ob)][n] (float4 over o) = sum_i x[n][i]*eW2[k][i*16+o..+3]
//           xb[ob][n] = sum_i x[n][i]*eb2[i*16+o..]
// Thread-per-node; LDS weight reads wave-uniform (broadcast); stores coalesced
// in the [k*4+ob][n] layout.
template<int DIN>
__global__ __launch_bounds__(256) void precompute_G(
        const float* __restrict__ x,
        const float* __restrict__ eW2,   // [16][DIN*16]
        const float* __restrict__ eb2,   // [DIN*16]
        float* __restrict__ G,           // float4 [64][NN]
        float* __restrict__ xb)          // float4 [4][NN]
{
    __shared__ __align__(16) float w2L[16 * DIN * 16];
    __shared__ __align__(16) float b2L[DIN * 16];
    int tid = threadIdx.x;
    for (int i = tid; i < 16 * DIN * 16; i += 256) w2L[i] = eW2[i];
    for (int i = tid; i < DIN * 16; i += 256) b2L[i] = eb2[i];
    __syncthreads();

    int n = blockIdx.x * 256 + tid;
    if (n >= NN) return;
    float xi[DIN];
#pragma unroll
    for (int i4 = 0; i4 < DIN / 4; ++i4)
        ((float4*)xi)[i4] = ((const float4*)(x + (size_t)n * DIN))[i4];

    const float4* w2v = (const float4*)w2L;
    const float4* b2v = (const float4*)b2L;
    float4* Gv  = (float4*)G;
    float4* xbv = (float4*)xb;

#pragma unroll
    for (int ob = 0; ob < 4; ++ob) {
        float4 acc = make_float4(0.f, 0.f, 0.f, 0.f);
#pragma unroll
        for (int i = 0; i < DIN; ++i) {
            float4 b = b2v[i * 4 + ob];
            acc.x += xi[i] * b.x; acc.y += xi[i] * b.y;
            acc.z += xi[i] * b.z; acc.w += xi[i] * b.w;
        }
        xbv[(size_t)ob * NN + n] = acc;
    }
#pragma unroll 1
    for (int k = 0; k < 16; ++k) {
#pragma unroll
        for (int ob = 0; ob < 4; ++ob) {
            float4 acc = make_float4(0.f, 0.f, 0.f, 0.f);
#pragma unroll
            for (int i = 0; i < DIN; ++i) {
                float4 w = w2v[(k * DIN + i) * 4 + ob];
                acc.x += xi[i] * w.x; acc.y += xi[i] * w.y;
                acc.z += xi[i] * w.z; acc.w += xi[i] * w.w;
            }
            Gv[(size_t)(k * 4 + ob) * NN + n] = acc;
        }
    }
}

// Edge message, src-sorted: msg = xb[src] + sum_k h[k]*G[k][src];
// scatter-store 64B row to dst-sorted slot. ~384 VALU ops + 68 near-coalesced
// vmem loads per edge; no atomics.
__global__ __launch_bounds__(256) void edge_msg(
        const int*   __restrict__ srcid,  // [NE] (sorted, near-uniform per wave)
        const int*   __restrict__ dstpos, // [NE]
        const float* __restrict__ ea_s,   // [NE][4] (src-sorted)
        const float* __restrict__ eW1,    // [4][16]
        const float* __restrict__ eb1,    // [16]
        const float* __restrict__ G,      // float4 [64][NN]
        const float* __restrict__ xb,     // float4 [4][NN]
        float* __restrict__ msgbuf)       // [NE][16]
{
    __shared__ __align__(16) float4 w1t[16];  // w1t[j] = eW1[:,j]
    __shared__ __align__(16) float  b1s[16];
    int tid = threadIdx.x;
    if (tid < 16) {
        w1t[tid] = make_float4(eW1[tid], eW1[16 + tid], eW1[32 + tid], eW1[48 + tid]);
        b1s[tid] = eb1[tid];
    }
    __syncthreads();

    int pos = blockIdx.x * 256 + tid;
    int src = srcid[pos];
    int dp  = dstpos[pos];
    float4 a = ((const float4*)ea_s)[pos];

    float h[16];
#pragma unroll
    for (int j = 0; j < 16; ++j) {
        float4 w = w1t[j];
        float p = b1s[j] + a.x * w.x + a.y * w.y + a.z * w.z + a.w * w.w;
        h[j] = p * sigm(p);
    }

    const float4* Gv  = (const float4*)G;
    const float4* xbv = (const float4*)xb;
    float4 acc[4];
#pragma unroll
    for (int ob = 0; ob < 4; ++ob) acc[ob] = xbv[(size_t)ob * NN + src];
#pragma unroll
    for (int k = 0; k < 16; ++k) {
        float hk = h[k];
#pragma unroll
        for (int ob = 0; ob < 4; ++ob) {
            float4 g = Gv[(size_t)(k * 4 + ob) * NN + src];
            acc[ob].x += hk * g.x; acc[ob].y += hk * g.y;
            acc[ob].z += hk * g.z; acc[ob].w += hk * g.w;
        }
    }
    float4* mrow = (float4*)(msgbuf + (size_t)dp * 16);
#pragma unroll
    for (int ob = 0; ob < 4; ++ob) mrow[ob] = acc[ob];
}

// ===========================================================================
// FALLBACK PATH (R5, proven 462us, 58MB ws)
// ===========================================================================
__global__ void build_rank_fb(const int* __restrict__ ei,
                              int* __restrict__ cnt_i,
                              int* __restrict__ rank)
{
    int e = blockIdx.x * 256 + threadIdx.x;
    rank[e] = atomicAdd(cnt_i + ei[NE + e], 1);
}

template<int DIN>
__global__ __launch_bounds__(256) void edge_compute_fb(
        const int*   __restrict__ ei,
        const float* __restrict__ ea,
        const float* __restrict__ eW1,
        const float* __restrict__ eb1,
        const float* __restrict__ eW2,
        const float* __restrict__ eb2,
        const float* __restrict__ xin,
        const int*   __restrict__ offset,
        const int*   __restrict__ rank,
        float*       __restrict__ msgbuf)
{
    __shared__ __align__(16) float w1[64];
    __shared__ __align__(16) float b1[16];
    __shared__ __align__(16) float w2[16 * DIN * 16];
    __shared__ __align__(16) float b2[DIN * 16];
    int tid = threadIdx.x;
    if (tid < 64) w1[tid] = eW1[tid];
    if (tid < 16) b1[tid] = eb1[tid];
    for (int i = tid; i < 16 * DIN * 16; i += 256) w2[i] = eW2[i];
    for (int i = tid; i < DIN * 16; i += 256) b2[i] = eb2[i];
    __syncthreads();

    int e = blockIdx.x * 256 + tid;
    int src = ei[e];
    int dst = ei[NE + e];
    int pos = offset[dst] + rank[e];
    float4 a = ((const float4*)ea)[e];

    float h[16];
#pragma unroll
    for (int j = 0; j < 16; ++j) {
        float p = b1[j] + a.x * w1[j] + a.y * w1[16 + j] + a.z * w1[32 + j] + a.w * w1[48 + j];
        h[j] = p * sigm(p);
    }
    float xs[DIN];
#pragma unroll
    for (int i4 = 0; i4 < DIN / 4; ++i4)
        ((float4*)xs)[i4] = ((const float4*)(xin + (size_t)src * DIN))[i4];

    float4* mrow = (float4*)(msgbuf + (size_t)pos * 16);
#pragma unroll 1
    for (int ob = 0; ob < 4; ++ob) {
        float4 acc = make_float4(0.f, 0.f, 0.f, 0.f);
#pragma unroll
        for (int i = 0; i < DIN; ++i) {
            float4 w = *((const float4*)(b2 + i * 16) + ob);
#pragma unroll
            for (int k = 0; k < 16; ++k) {
                float4 g = *((const float4*)(w2 + (k * DIN + i) * 16) + ob);
                w.x += h[k] * g.x; w.y += h[k] * g.y;
                w.z += h[k] * g.z; w.w += h[k] * g.w;
            }
            acc.x += xs[i] * w.x; acc.y += xs[i] * w.y;
            acc.z += xs[i] * w.z; acc.w += xs[i] * w.w;
        }
        mrow[ob] = acc;
    }
}

// ===========================================================================
// Host launch
// ===========================================================================
extern "C" void kernel_launch(void* const* d_in, const int* in_sizes, int n_in,
                              void* d_out, int out_size, void* d_ws, size_t ws_size,
                              hipStream_t stream) {
    const float* x     = (const float*)d_in[0];
    const int*   ei    = (const int*)  d_in[1];
    const float* ea    = (const float*)d_in[2];
    const float* eW1_0 = (const float*)d_in[3];
    const float* eb1_0 = (const float*)d_in[4];
    const float* eW2_0 = (const float*)d_in[5];
    const float* eb2_0 = (const float*)d_in[6];
    const float* root0 = (const float*)d_in[7];
    const float* bias0 = (const float*)d_in[8];
    const float* eW1_1 = (const float*)d_in[9];
    const float* eb1_1 = (const float*)d_in[10];
    const float* eW2_1 = (const float*)d_in[11];
    const float* eb2_1 = (const float*)d_in[12];
    const float* root1 = (const float*)d_in[13];
    const float* bias1 = (const float*)d_in[14];
    const float* mW1   = (const float*)d_in[15];
    const float* mb1   = (const float*)d_in[16];
    const float* mW2   = (const float*)d_in[17];
    const float* mb2   = (const float*)d_in[18];
    float* out = (float*)d_out;

    const int EG = NE / 256;   // 3125
    const int GG = NN / 16;    // 3125
    const int PG = (NN + 255) / 256;  // 196

    // ---- new-path ws layout (4B words) ----
    int*   W      = (int*)d_ws;
    int*   off_d  = W;                    // NN+1
    int*   off_s  = W + 50004;            // NN+1
    int*   cnt_d  = W + 100008;           // NN
    int*   cnt_s  = W + 150008;           // NN   (cnt_d..cnt_s contiguous)
    float* xbuf   = (float*)(W + 200008); // xb: float4 [4][NN] = 800000 f
    float* x1     = (float*)(W + 1000008);// [NN][16]
    int*   srcid  = W + 1800008;          // NE
    int*   dstpos = W + 2600008;          // NE
    int*   rank_d = W + 3400008;          // NE
    int*   rank_s = W + 4200008;          // NE
    float* ea_s   = (float*)(W + 5000008);  // [NE][4]
    float* G      = (float*)(W + 8200008);  // float4 [64][NN] = 12.8M f
    float* msgbuf = (float*)(W + 21000008); // [NE][16] = 12.8M f
    const size_t needNew = (size_t)33800008 * 4;  // 135.2 MB

    if (ws_size >= needNew) {
        hipMemsetAsync(cnt_d, 0, 2 * NN * sizeof(int), stream);
        build_ranks<<<EG, 256, 0, stream>>>(ei, cnt_s, cnt_d, rank_s, rank_d);
        scan_offsets<<<1, 256, 0, stream>>>(cnt_d, off_d);
        scan_offsets<<<1, 256, 0, stream>>>(cnt_s, off_s);
        build_perm<<<EG, 256, 0, stream>>>(ei, ea, off_s, off_d, rank_s, rank_d,
                                           srcid, dstpos, ea_s);
        // ---- layer 0 ----
        precompute_G<8><<<PG, 256, 0, stream>>>(x, eW2_0, eb2_0, G, xbuf);
        edge_msg<<<EG, 256, 0, stream>>>(srcid, dstpos, ea_s, eW1_0, eb1_0, G, xbuf, msgbuf);
        gather_nodes<8, false><<<GG, 256, 0, stream>>>(x, root0, bias0, off_d, msgbuf,
                                                       mW1, mb1, mW2, mb2, x1);
        // ---- layer 1 ----
        precompute_G<16><<<PG, 256, 0, stream>>>(x1, eW2_1, eb2_1, G, xbuf);
        edge_msg<<<EG, 256, 0, stream>>>(srcid, dstpos, ea_s, eW1_1, eb1_1, G, xbuf, msgbuf);
        gather_nodes<16, true><<<GG, 256, 0, stream>>>(x1, root1, bias1, off_d, msgbuf,
                                                       mW1, mb1, mW2, mb2, out);
    } else {
        // ---- R5 fallback (58 MB) ----
        int*   cnt_i  = (int*)d_ws;
        int*   offset = cnt_i + NN;
        int*   rank   = (int*)d_ws + 100004;
        float* msgb   = (float*)d_ws + 900004;
        float* x1f    = (float*)d_ws + 13700004;

        hipMemsetAsync(cnt_i, 0, NN * sizeof(int), stream);
        build_rank_fb<<<EG, 256, 0, stream>>>(ei, cnt_i, rank);
        scan_offsets<<<1, 256, 0, stream>>>(cnt_i, offset);
        edge_compute_fb<8><<<EG, 256, 0, stream>>>(ei, ea, eW1_0, eb1_0, eW2_0, eb2_0,
                                                   x, offset, rank, msgb);
        gather_nodes<8, false><<<GG, 256, 0, stream>>>(x, root0, bias0, offset, msgb,
                                                       mW1, mb1, mW2, mb2, x1f);
        edge_compute_fb<16><<<EG, 256, 0, stream>>>(ei, ea, eW1_1, eb1_1, eW2_1, eb2_1,
                                                    x1f, offset, rank, msgb);
        gather_nodes<16, true><<<GG, 256, 0, stream>>>(x1f, root1, bias1, offset, msgb,
                                                       mW1, mb1, mW2, mb2, out);
    }
}

// Round 7
// 383.529 us; speedup vs baseline: 1.3910x; 1.3910x over previous
//
#include <hip/hip_runtime.h>

#define NN 50000
#define NE 800000

__device__ __forceinline__ float sigm(float v) { return 1.0f / (1.0f + __expf(-v)); }

// ===========================================================================
// Hierarchical exclusive scan (3 kernels), n up to 512*256 elements.
// K1: per-block sums. K2: 1-block exclusive scan of block sums. K3: per-block
// exclusive scan + base, writes offset[0..n] (offset[n] = total).
// ===========================================================================
__global__ void scan_k1(const int* __restrict__ cnt, int n,
                        int* __restrict__ bsum)
{
    __shared__ int s[256];
    int t = threadIdx.x;
    int idx = blockIdx.x * 256 + t;
    int v = (idx < n) ? cnt[idx] : 0;
    s[t] = v;
    __syncthreads();
#pragma unroll
    for (int d = 128; d; d >>= 1) {
        if (t < d) s[t] += s[t + d];
        __syncthreads();
    }
    if (t == 0) bsum[blockIdx.x] = s[0];
}

__global__ void scan_k2(int* __restrict__ bsum, int nblocks)
{
    __shared__ int s[512];
    int t = threadIdx.x;
    int v = (t < nblocks) ? bsum[t] : 0;
    s[t] = v;
    __syncthreads();
#pragma unroll
    for (int d = 1; d < 512; d <<= 1) {
        int a = (t >= d) ? s[t - d] : 0;
        __syncthreads();
        s[t] += a;
        __syncthreads();
    }
    if (t < nblocks) bsum[t] = s[t] - v;   // exclusive
}

__global__ void scan_k3(const int* __restrict__ cnt, int n,
                        const int* __restrict__ bsum,
                        int* __restrict__ offset)
{
    __shared__ int s[256];
    int t = threadIdx.x;
    int idx = blockIdx.x * 256 + t;
    int v = (idx < n) ? cnt[idx] : 0;
    s[t] = v;
    __syncthreads();
#pragma unroll
    for (int d = 1; d < 256; d <<= 1) {
        int a = (t >= d) ? s[t - d] : 0;
        __syncthreads();
        s[t] += a;
        __syncthreads();
    }
    if (idx <= n) offset[idx] = bsum[blockIdx.x] + s[t] - v;
}

// ===========================================================================
// Graph prep (int atomics only; graph static -> once per launch)
// ===========================================================================
__global__ void build_ranks(const int* __restrict__ ei,
                            int* __restrict__ cnt_d, int* __restrict__ cnt_s,
                            int* __restrict__ rank_s, int* __restrict__ rank_d)
{
    int e = blockIdx.x * 256 + threadIdx.x;   // NE == 3125*256 exactly
    int s = ei[e], d = ei[NE + e];
    rank_s[e] = atomicAdd(cnt_s + s, 1);
    rank_d[e] = atomicAdd(cnt_d + d, 1);
}

// off_all: combined exclusive scan of [cnt_d | cnt_s]; off_s[s] = off_all[NN+s]-NE.
__global__ void build_perm(const int* __restrict__ ei,
                           const float* __restrict__ ea,
                           const int* __restrict__ off_all,
                           const int* __restrict__ rank_s, const int* __restrict__ rank_d,
                           int* __restrict__ srcid, int* __restrict__ dstpos,
                           float* __restrict__ ea_s)
{
    int e = blockIdx.x * 256 + threadIdx.x;
    int s = ei[e], d = ei[NE + e];
    int pos = off_all[NN + s] - NE + rank_s[e];
    srcid[pos]  = s;
    dstpos[pos] = off_all[d] + rank_d[e];
    ((float4*)ea_s)[pos] = ((const float4*)ea)[e];
}

// ===========================================================================
// Per-node: G[(k*4+ob)][n] (float4 over o) = sum_i x[n][i]*eW2[k][i*16+o..+3]
//           xb[ob][n] = sum_i x[n][i]*eb2[i*16+o..]
// ===========================================================================
template<int DIN>
__global__ __launch_bounds__(256) void precompute_G(
        const float* __restrict__ x,
        const float* __restrict__ eW2,   // [16][DIN*16]
        const float* __restrict__ eb2,   // [DIN*16]
        float* __restrict__ G,           // float4 [64][NN]
        float* __restrict__ xb)          // float4 [4][NN]
{
    __shared__ __align__(16) float w2L[16 * DIN * 16];
    __shared__ __align__(16) float b2L[DIN * 16];
    int tid = threadIdx.x;
    for (int i = tid; i < 16 * DIN * 16; i += 256) w2L[i] = eW2[i];
    for (int i = tid; i < DIN * 16; i += 256) b2L[i] = eb2[i];
    __syncthreads();

    int n = blockIdx.x * 256 + tid;
    if (n >= NN) return;
    float xi[DIN];
#pragma unroll
    for (int i4 = 0; i4 < DIN / 4; ++i4)
        ((float4*)xi)[i4] = ((const float4*)(x + (size_t)n * DIN))[i4];

    const float4* w2v = (const float4*)w2L;
    const float4* b2v = (const float4*)b2L;
    float4* Gv  = (float4*)G;
    float4* xbv = (float4*)xb;

#pragma unroll
    for (int ob = 0; ob < 4; ++ob) {
        float4 acc = make_float4(0.f, 0.f, 0.f, 0.f);
#pragma unroll
        for (int i = 0; i < DIN; ++i) {
            float4 b = b2v[i * 4 + ob];
            acc.x += xi[i] * b.x; acc.y += xi[i] * b.y;
            acc.z += xi[i] * b.z; acc.w += xi[i] * b.w;
        }
        xbv[(size_t)ob * NN + n] = acc;
    }
#pragma unroll 1
    for (int k = 0; k < 16; ++k) {
#pragma unroll
        for (int ob = 0; ob < 4; ++ob) {
            float4 acc = make_float4(0.f, 0.f, 0.f, 0.f);
#pragma unroll
            for (int i = 0; i < DIN; ++i) {
                float4 w = w2v[(k * DIN + i) * 4 + ob];
                acc.x += xi[i] * w.x; acc.y += xi[i] * w.y;
                acc.z += xi[i] * w.z; acc.w += xi[i] * w.w;
            }
            Gv[(size_t)(k * 4 + ob) * NN + n] = acc;
        }
    }
}

// ===========================================================================
// Edge message, src-sorted: msg = xb[src] + sum_k h[k]*G[k][src];
// scatter-store 64B row to dst-sorted slot. No atomics.
// ===========================================================================
__global__ __launch_bounds__(256) void edge_msg(
        const int*   __restrict__ srcid,  // [NE] (sorted, ~4-5 distinct/wave)
        const int*   __restrict__ dstpos, // [NE]
        const float* __restrict__ ea_s,   // [NE][4] (src-sorted)
        const float* __restrict__ eW1,    // [4][16]
        const float* __restrict__ eb1,    // [16]
        const float* __restrict__ G,      // float4 [64][NN]
        const float* __restrict__ xb,     // float4 [4][NN]
        float* __restrict__ msgbuf)       // [NE][16]
{
    __shared__ __align__(16) float4 w1t[16];  // w1t[j] = eW1[:,j]
    __shared__ __align__(16) float  b1s[16];
    int tid = threadIdx.x;
    if (tid < 16) {
        w1t[tid] = make_float4(eW1[tid], eW1[16 + tid], eW1[32 + tid], eW1[48 + tid]);
        b1s[tid] = eb1[tid];
    }
    __syncthreads();

    int pos = blockIdx.x * 256 + tid;
    int src = srcid[pos];
    int dp  = dstpos[pos];
    float4 a = ((const float4*)ea_s)[pos];

    float h[16];
#pragma unroll
    for (int j = 0; j < 16; ++j) {
        float4 w = w1t[j];
        float p = b1s[j] + a.x * w.x + a.y * w.y + a.z * w.z + a.w * w.w;
        h[j] = p * sigm(p);
    }

    const float4* Gv  = (const float4*)G;
    const float4* xbv = (const float4*)xb;
    float4 acc[4];
#pragma unroll
    for (int ob = 0; ob < 4; ++ob) acc[ob] = xbv[(size_t)ob * NN + src];
#pragma unroll
    for (int k = 0; k < 16; ++k) {
        float hk = h[k];
#pragma unroll
        for (int ob = 0; ob < 4; ++ob) {
            float4 g = Gv[(size_t)(k * 4 + ob) * NN + src];
            acc[ob].x += hk * g.x; acc[ob].y += hk * g.y;
            acc[ob].z += hk * g.z; acc[ob].w += hk * g.w;
        }
    }
    float4* mrow = (float4*)(msgbuf + (size_t)dp * 16);
#pragma unroll
    for (int ob = 0; ob < 4; ++ob) mrow[ob] = acc[ob];
}

// ===========================================================================
// Gather: 16-lane group per node sums its contiguous msg rows (coalesced,
// no atomics), then fused node update (+ output MLP when FINAL).
// offset = off_all (dst part).
// ===========================================================================
template<int DIN, bool FINAL>
__global__ __launch_bounds__(256) void gather_nodes(
        const float* __restrict__ xin,    // [NN][DIN]
        const float* __restrict__ root,   // [DIN][16]
        const float* __restrict__ bias,   // [16]
        const int*   __restrict__ offset, // [NN+1] (dst CSR)
        const float* __restrict__ msgbuf, // [NE][16]
        const float* __restrict__ mW1,    // [16][16] (FINAL)
        const float* __restrict__ mb1,    // [16]
        const float* __restrict__ mW2,    // [16]
        const float* __restrict__ mb2,    // [1]
        float* __restrict__ xout)         // [NN][16] or [NN]
{
    __shared__ __align__(16) float rootL[DIN * 16];
    __shared__ __align__(16) float biasL[16];
    __shared__ __align__(16) float w1m[256];
    __shared__ __align__(16) float b1m[16];
    __shared__ __align__(16) float w2m[16];
    __shared__ float b2m;
    int tid = threadIdx.x;
    for (int i = tid; i < DIN * 16; i += 256) rootL[i] = root[i];
    if (tid < 16) biasL[tid] = bias[tid];
    if constexpr (FINAL) {
        w1m[tid] = mW1[tid];
        if (tid < 16) { b1m[tid] = mb1[tid]; w2m[tid] = mW2[tid]; }
        if (tid == 0) b2m = mb2[0];
    }
    __syncthreads();

    int ch = tid & 15;
    int n  = blockIdx.x * 16 + (tid >> 4);   // NN == 3125*16 exactly
    int s  = offset[n];
    int epos = offset[n + 1];
    int deg = epos - s;

    float acc = 0.f;
    for (int j = s; j < epos; ++j)
        acc += msgbuf[(size_t)j * 16 + ch];

    float v = acc / fmaxf((float)deg, 1.0f) + biasL[ch];
#pragma unroll
    for (int i = 0; i < DIN; ++i)
        v += xin[(size_t)n * DIN + i] * rootL[i * 16 + ch];
    v = fmaxf(v, 0.f);

    if constexpr (!FINAL) {
        xout[(size_t)n * 16 + ch] = v;
    } else {
        float z = b1m[ch];
#pragma unroll
        for (int o = 0; o < 16; ++o) {
            float vo = __shfl(v, o, 16);
            z += vo * w1m[o * 16 + ch];
        }
        float ss = z * sigm(z) * w2m[ch];
#pragma unroll
        for (int off = 8; off; off >>= 1) ss += __shfl_xor(ss, off, 16);
        if (ch == 0) xout[n] = sigm(ss + b2m);
    }
}

// ===========================================================================
// FALLBACK PATH (R5-style, 58 MB ws) -- only if ws_size < 135.2 MB
// ===========================================================================
__global__ void build_rank_fb(const int* __restrict__ ei,
                              int* __restrict__ cnt_i,
                              int* __restrict__ rank)
{
    int e = blockIdx.x * 256 + threadIdx.x;
    rank[e] = atomicAdd(cnt_i + ei[NE + e], 1);
}

template<int DIN>
__global__ __launch_bounds__(256) void edge_compute_fb(
        const int*   __restrict__ ei,
        const float* __restrict__ ea,
        const float* __restrict__ eW1,
        const float* __restrict__ eb1,
        const float* __restrict__ eW2,
        const float* __restrict__ eb2,
        const float* __restrict__ xin,
        const int*   __restrict__ offset,
        const int*   __restrict__ rank,
        float*       __restrict__ msgbuf)
{
    __shared__ __align__(16) float w1[64];
    __shared__ __align__(16) float b1[16];
    __shared__ __align__(16) float w2[16 * DIN * 16];
    __shared__ __align__(16) float b2[DIN * 16];
    int tid = threadIdx.x;
    if (tid < 64) w1[tid] = eW1[tid];
    if (tid < 16) b1[tid] = eb1[tid];
    for (int i = tid; i < 16 * DIN * 16; i += 256) w2[i] = eW2[i];
    for (int i = tid; i < DIN * 16; i += 256) b2[i] = eb2[i];
    __syncthreads();

    int e = blockIdx.x * 256 + tid;
    int src = ei[e];
    int dst = ei[NE + e];
    int pos = offset[dst] + rank[e];
    float4 a = ((const float4*)ea)[e];

    float h[16];
#pragma unroll
    for (int j = 0; j < 16; ++j) {
        float p = b1[j] + a.x * w1[j] + a.y * w1[16 + j] + a.z * w1[32 + j] + a.w * w1[48 + j];
        h[j] = p * sigm(p);
    }
    float xs[DIN];
#pragma unroll
    for (int i4 = 0; i4 < DIN / 4; ++i4)
        ((float4*)xs)[i4] = ((const float4*)(xin + (size_t)src * DIN))[i4];

    float4* mrow = (float4*)(msgbuf + (size_t)pos * 16);
#pragma unroll 1
    for (int ob = 0; ob < 4; ++ob) {
        float4 acc = make_float4(0.f, 0.f, 0.f, 0.f);
#pragma unroll
        for (int i = 0; i < DIN; ++i) {
            float4 w = *((const float4*)(b2 + i * 16) + ob);
#pragma unroll
            for (int k = 0; k < 16; ++k) {
                float4 g = *((const float4*)(w2 + (k * DIN + i) * 16) + ob);
                w.x += h[k] * g.x; w.y += h[k] * g.y;
                w.z += h[k] * g.z; w.w += h[k] * g.w;
            }
            acc.x += xs[i] * w.x; acc.y += xs[i] * w.y;
            acc.z += xs[i] * w.z; acc.w += xs[i] * w.w;
        }
        mrow[ob] = acc;
    }
}

// ===========================================================================
// Host launch
// ===========================================================================
extern "C" void kernel_launch(void* const* d_in, const int* in_sizes, int n_in,
                              void* d_out, int out_size, void* d_ws, size_t ws_size,
                              hipStream_t stream) {
    const float* x     = (const float*)d_in[0];
    const int*   ei    = (const int*)  d_in[1];
    const float* ea    = (const float*)d_in[2];
    const float* eW1_0 = (const float*)d_in[3];
    const float* eb1_0 = (const float*)d_in[4];
    const float* eW2_0 = (const float*)d_in[5];
    const float* eb2_0 = (const float*)d_in[6];
    const float* root0 = (const float*)d_in[7];
    const float* bias0 = (const float*)d_in[8];
    const float* eW1_1 = (const float*)d_in[9];
    const float* eb1_1 = (const float*)d_in[10];
    const float* eW2_1 = (const float*)d_in[11];
    const float* eb2_1 = (const float*)d_in[12];
    const float* root1 = (const float*)d_in[13];
    const float* bias1 = (const float*)d_in[14];
    const float* mW1   = (const float*)d_in[15];
    const float* mb1   = (const float*)d_in[16];
    const float* mW2   = (const float*)d_in[17];
    const float* mb2   = (const float*)d_in[18];
    float* out = (float*)d_out;

    const int EG = NE / 256;          // 3125
    const int GG = NN / 16;           // 3125
    const int PG = (NN + 255) / 256;  // 196

    // ---- new-path ws layout (4B words) ----
    int*   W       = (int*)d_ws;
    int*   cnt_all = W;                     // [0, 100000): cnt_d | cnt_s
    int*   off_all = W + 100000;            // [100000, 200002)
    int*   bsum    = W + 200004;            // [200004, 200516)
    int*   rank_s  = W + 200516;            // NE
    int*   rank_d  = W + 1000516;           // NE
    int*   srcid   = W + 1800516;           // NE
    int*   dstpos  = W + 2600516;           // NE
    float* x1      = (float*)(W + 3400516); // [NN][16]
    float* ea_s    = (float*)(W + 4200516); // [NE][4]
    float* xbuf    = (float*)(W + 7400516); // float4 [4][NN]
    float* G       = (float*)(W + 8200516); // float4 [64][NN]
    float* msgbuf  = (float*)(W + 21000516);// [NE][16]
    const size_t needNew = (size_t)33800516 * 4;  // 135.2 MB

    if (ws_size >= needNew) {
        const int SN = 2 * NN;                 // combined scan length
        const int SB = (SN + 256) / 256 + ((SN + 1) % 256 ? 0 : 0); // 391
        hipMemsetAsync(cnt_all, 0, SN * sizeof(int), stream);
        build_ranks<<<EG, 256, 0, stream>>>(ei, cnt_all, cnt_all + NN, rank_s, rank_d);
        scan_k1<<<SB, 256, 0, stream>>>(cnt_all, SN, bsum);
        scan_k2<<<1, 512, 0, stream>>>(bsum, SB);
        scan_k3<<<SB, 256, 0, stream>>>(cnt_all, SN, bsum, off_all);
        build_perm<<<EG, 256, 0, stream>>>(ei, ea, off_all, rank_s, rank_d,
                                           srcid, dstpos, ea_s);
        // ---- layer 0 ----
        precompute_G<8><<<PG, 256, 0, stream>>>(x, eW2_0, eb2_0, G, xbuf);
        edge_msg<<<EG, 256, 0, stream>>>(srcid, dstpos, ea_s, eW1_0, eb1_0, G, xbuf, msgbuf);
        gather_nodes<8, false><<<GG, 256, 0, stream>>>(x, root0, bias0, off_all, msgbuf,
                                                       mW1, mb1, mW2, mb2, x1);
        // ---- layer 1 ----
        precompute_G<16><<<PG, 256, 0, stream>>>(x1, eW2_1, eb2_1, G, xbuf);
        edge_msg<<<EG, 256, 0, stream>>>(srcid, dstpos, ea_s, eW1_1, eb1_1, G, xbuf, msgbuf);
        gather_nodes<16, true><<<GG, 256, 0, stream>>>(x1, root1, bias1, off_all, msgbuf,
                                                       mW1, mb1, mW2, mb2, out);
    } else {
        // ---- fallback (58 MB): R5 structure with fast scan ----
        int*   cnt_i  = (int*)d_ws;                 // NN
        int*   offset = cnt_i + NN;                 // NN+1
        int*   bsumF  = (int*)d_ws + 100004;        // 512
        int*   rank   = (int*)d_ws + 100516;        // NE
        float* msgb   = (float*)d_ws + 900516;      // [NE][16]
        float* x1f    = (float*)d_ws + 13700516;    // [NN][16]
        const int FB = (NN + 1 + 255) / 256;        // 196

        hipMemsetAsync(cnt_i, 0, NN * sizeof(int), stream);
        build_rank_fb<<<EG, 256, 0, stream>>>(ei, cnt_i, rank);
        scan_k1<<<FB, 256, 0, stream>>>(cnt_i, NN, bsumF);
        scan_k2<<<1, 512, 0, stream>>>(bsumF, FB);
        scan_k3<<<FB, 256, 0, stream>>>(cnt_i, NN, bsumF, offset);
        edge_compute_fb<8><<<EG, 256, 0, stream>>>(ei, ea, eW1_0, eb1_0, eW2_0, eb2_0,
                                                   x, offset, rank, msgb);
        gather_nodes<8, false><<<GG, 256, 0, stream>>>(x, root0, bias0, offset, msgb,
                                                       mW1, mb1, mW2, mb2, x1f);
        edge_compute_fb<16><<<EG, 256, 0, stream>>>(ei, ea, eW1_1, eb1_1, eW2_1, eb2_1,
                                                    x1f, offset, rank, msgb);
        gather_nodes<16, true><<<GG, 256, 0, stream>>>(x1f, root1, bias1, offset, msgb,
                                                       mW1, mb1, mW2, mb2, out);
    }
}

// Round 8
// 369.488 us; speedup vs baseline: 1.4439x; 1.0380x over previous
//
#include <hip/hip_runtime.h>

#define NN 50000
#define NE 800000

__device__ __forceinline__ float sigm(float v) { return 1.0f / (1.0f + __expf(-v)); }

// ===========================================================================
// Hierarchical exclusive scan (3 kernels), n up to 512*256 elements.
// ===========================================================================
__global__ void scan_k1(const int* __restrict__ cnt, int n,
                        int* __restrict__ bsum)
{
    __shared__ int s[256];
    int t = threadIdx.x;
    int idx = blockIdx.x * 256 + t;
    int v = (idx < n) ? cnt[idx] : 0;
    s[t] = v;
    __syncthreads();
#pragma unroll
    for (int d = 128; d; d >>= 1) {
        if (t < d) s[t] += s[t + d];
        __syncthreads();
    }
    if (t == 0) bsum[blockIdx.x] = s[0];
}

__global__ void scan_k2(int* __restrict__ bsum, int nblocks)
{
    __shared__ int s[512];
    int t = threadIdx.x;
    int v = (t < nblocks) ? bsum[t] : 0;
    s[t] = v;
    __syncthreads();
#pragma unroll
    for (int d = 1; d < 512; d <<= 1) {
        int a = (t >= d) ? s[t - d] : 0;
        __syncthreads();
        s[t] += a;
        __syncthreads();
    }
    if (t < nblocks) bsum[t] = s[t] - v;   // exclusive
}

__global__ void scan_k3(const int* __restrict__ cnt, int n,
                        const int* __restrict__ bsum,
                        int* __restrict__ offset)
{
    __shared__ int s[256];
    int t = threadIdx.x;
    int idx = blockIdx.x * 256 + t;
    int v = (idx < n) ? cnt[idx] : 0;
    s[t] = v;
    __syncthreads();
#pragma unroll
    for (int d = 1; d < 256; d <<= 1) {
        int a = (t >= d) ? s[t - d] : 0;
        __syncthreads();
        s[t] += a;
        __syncthreads();
    }
    if (idx <= n) offset[idx] = bsum[blockIdx.x] + s[t] - v;
}

// ===========================================================================
// Graph prep. build_ranks: 4 edges/thread -> 8 independent atomics in flight
// per lane (R7 showed this kernel is atomic-LATENCY-bound at ~8/cyc chip-wide
// with only 2 outstanding per lane; MLP is the lever, not contention).
// ===========================================================================
__global__ void build_ranks(const int* __restrict__ ei,
                            int* __restrict__ cnt_d, int* __restrict__ cnt_s,
                            int* __restrict__ rank_s, int* __restrict__ rank_d)
{
    int base = blockIdx.x * 1024 + threadIdx.x;
    int s[4], d[4], e[4];
    bool val[4];
#pragma unroll
    for (int q = 0; q < 4; ++q) {
        e[q] = base + q * 256;
        val[q] = e[q] < NE;
        if (val[q]) { s[q] = ei[e[q]]; d[q] = ei[NE + e[q]]; }
    }
#pragma unroll
    for (int q = 0; q < 4; ++q)
        if (val[q]) rank_s[e[q]] = atomicAdd(cnt_s + s[q], 1);
#pragma unroll
    for (int q = 0; q < 4; ++q)
        if (val[q]) rank_d[e[q]] = atomicAdd(cnt_d + d[q], 1);
}

// off_all: combined exclusive scan of [cnt_d | cnt_s]; off_s[s] = off_all[NN+s]-NE.
// pack[pos] = (src << 20) | dstpos  (src < 2^16, dstpos < 2^20).
__global__ void build_perm(const int* __restrict__ ei,
                           const float* __restrict__ ea,
                           const int* __restrict__ off_all,
                           const int* __restrict__ rank_s, const int* __restrict__ rank_d,
                           unsigned long long* __restrict__ pack,
                           float* __restrict__ ea_s)
{
    int e = blockIdx.x * 256 + threadIdx.x;
    int s = ei[e], d = ei[NE + e];
    int pos = off_all[NN + s] - NE + rank_s[e];
    int dp  = off_all[d] + rank_d[e];
    pack[pos] = ((unsigned long long)s << 20) | (unsigned long long)dp;
    ((float4*)ea_s)[pos] = ((const float4*)ea)[e];
}

// ===========================================================================
// Per-node: G[(k*4+ob)][n] (float4 over o) = sum_i x[n][i]*eW2[k][i*16+o..+3]
//           xb[ob][n] = sum_i x[n][i]*eb2[i*16+o..]
// ===========================================================================
template<int DIN>
__global__ __launch_bounds__(256) void precompute_G(
        const float* __restrict__ x,
        const float* __restrict__ eW2,   // [16][DIN*16]
        const float* __restrict__ eb2,   // [DIN*16]
        float* __restrict__ G,           // float4 [64][NN]
        float* __restrict__ xb)          // float4 [4][NN]
{
    __shared__ __align__(16) float w2L[16 * DIN * 16];
    __shared__ __align__(16) float b2L[DIN * 16];
    int tid = threadIdx.x;
    for (int i = tid; i < 16 * DIN * 16; i += 256) w2L[i] = eW2[i];
    for (int i = tid; i < DIN * 16; i += 256) b2L[i] = eb2[i];
    __syncthreads();

    int n = blockIdx.x * 256 + tid;
    if (n >= NN) return;
    float xi[DIN];
#pragma unroll
    for (int i4 = 0; i4 < DIN / 4; ++i4)
        ((float4*)xi)[i4] = ((const float4*)(x + (size_t)n * DIN))[i4];

    const float4* w2v = (const float4*)w2L;
    const float4* b2v = (const float4*)b2L;
    float4* Gv  = (float4*)G;
    float4* xbv = (float4*)xb;

#pragma unroll
    for (int ob = 0; ob < 4; ++ob) {
        float4 acc = make_float4(0.f, 0.f, 0.f, 0.f);
#pragma unroll
        for (int i = 0; i < DIN; ++i) {
            float4 b = b2v[i * 4 + ob];
            acc.x += xi[i] * b.x; acc.y += xi[i] * b.y;
            acc.z += xi[i] * b.z; acc.w += xi[i] * b.w;
        }
        xbv[(size_t)ob * NN + n] = acc;
    }
#pragma unroll 1
    for (int k = 0; k < 16; ++k) {
#pragma unroll
        for (int ob = 0; ob < 4; ++ob) {
            float4 acc = make_float4(0.f, 0.f, 0.f, 0.f);
#pragma unroll
            for (int i = 0; i < DIN; ++i) {
                float4 w = w2v[(k * DIN + i) * 4 + ob];
                acc.x += xi[i] * w.x; acc.y += xi[i] * w.y;
                acc.z += xi[i] * w.z; acc.w += xi[i] * w.w;
            }
            Gv[(size_t)(k * 4 + ob) * NN + n] = acc;
        }
    }
}

// ===========================================================================
// Edge message, src-sorted: msg = xb[src] + sum_k h[k]*G[k][src];
// scatter-store 64B row to dst-sorted slot. No atomics.
// ===========================================================================
__global__ __launch_bounds__(256) void edge_msg(
        const unsigned long long* __restrict__ pack,  // [NE] (src<<20)|dstpos
        const float* __restrict__ ea_s,   // [NE][4] (src-sorted)
        const float* __restrict__ eW1,    // [4][16]
        const float* __restrict__ eb1,    // [16]
        const float* __restrict__ G,      // float4 [64][NN]
        const float* __restrict__ xb,     // float4 [4][NN]
        float* __restrict__ msgbuf)       // [NE][16]
{
    __shared__ __align__(16) float4 w1t[16];  // w1t[j] = eW1[:,j]
    __shared__ __align__(16) float  b1s[16];
    int tid = threadIdx.x;
    if (tid < 16) {
        w1t[tid] = make_float4(eW1[tid], eW1[16 + tid], eW1[32 + tid], eW1[48 + tid]);
        b1s[tid] = eb1[tid];
    }
    __syncthreads();

    int pos = blockIdx.x * 256 + tid;
    unsigned long long pk = pack[pos];
    int dp  = (int)(pk & 0xFFFFFu);
    int src = (int)(pk >> 20);
    float4 a = ((const float4*)ea_s)[pos];

    float h[16];
#pragma unroll
    for (int j = 0; j < 16; ++j) {
        float4 w = w1t[j];
        float p = b1s[j] + a.x * w.x + a.y * w.y + a.z * w.z + a.w * w.w;
        h[j] = p * sigm(p);
    }

    const float4* Gv  = (const float4*)G;
    const float4* xbv = (const float4*)xb;
    float4 acc[4];
#pragma unroll
    for (int ob = 0; ob < 4; ++ob) acc[ob] = xbv[(size_t)ob * NN + src];
#pragma unroll
    for (int k = 0; k < 16; ++k) {
        float hk = h[k];
#pragma unroll
        for (int ob = 0; ob < 4; ++ob) {
            float4 g = Gv[(size_t)(k * 4 + ob) * NN + src];
            acc[ob].x += hk * g.x; acc[ob].y += hk * g.y;
            acc[ob].z += hk * g.z; acc[ob].w += hk * g.w;
        }
    }
    float4* mrow = (float4*)(msgbuf + (size_t)dp * 16);
#pragma unroll
    for (int ob = 0; ob < 4; ++ob) mrow[ob] = acc[ob];
}

// ===========================================================================
// Gather: 16-lane group per node sums its contiguous msg rows (coalesced,
// no atomics), then fused node update (+ output MLP when FINAL).
// ===========================================================================
template<int DIN, bool FINAL>
__global__ __launch_bounds__(256) void gather_nodes(
        const float* __restrict__ xin,    // [NN][DIN]
        const float* __restrict__ root,   // [DIN][16]
        const float* __restrict__ bias,   // [16]
        const int*   __restrict__ offset, // [NN+1] (dst CSR)
        const float* __restrict__ msgbuf, // [NE][16]
        const float* __restrict__ mW1,    // [16][16] (FINAL)
        const float* __restrict__ mb1,    // [16]
        const float* __restrict__ mW2,    // [16]
        const float* __restrict__ mb2,    // [1]
        float* __restrict__ xout)         // [NN][16] or [NN]
{
    __shared__ __align__(16) float rootL[DIN * 16];
    __shared__ __align__(16) float biasL[16];
    __shared__ __align__(16) float w1m[256];
    __shared__ __align__(16) float b1m[16];
    __shared__ __align__(16) float w2m[16];
    __shared__ float b2m;
    int tid = threadIdx.x;
    for (int i = tid; i < DIN * 16; i += 256) rootL[i] = root[i];
    if (tid < 16) biasL[tid] = bias[tid];
    if constexpr (FINAL) {
        w1m[tid] = mW1[tid];
        if (tid < 16) { b1m[tid] = mb1[tid]; w2m[tid] = mW2[tid]; }
        if (tid == 0) b2m = mb2[0];
    }
    __syncthreads();

    int ch = tid & 15;
    int n  = blockIdx.x * 16 + (tid >> 4);   // NN == 3125*16 exactly
    int s  = offset[n];
    int epos = offset[n + 1];
    int deg = epos - s;

    float acc = 0.f;
    for (int j = s; j < epos; ++j)
        acc += msgbuf[(size_t)j * 16 + ch];

    float v = acc / fmaxf((float)deg, 1.0f) + biasL[ch];
#pragma unroll
    for (int i = 0; i < DIN; ++i)
        v += xin[(size_t)n * DIN + i] * rootL[i * 16 + ch];
    v = fmaxf(v, 0.f);

    if constexpr (!FINAL) {
        xout[(size_t)n * 16 + ch] = v;
    } else {
        float z = b1m[ch];
#pragma unroll
        for (int o = 0; o < 16; ++o) {
            float vo = __shfl(v, o, 16);
            z += vo * w1m[o * 16 + ch];
        }
        float ss = z * sigm(z) * w2m[ch];
#pragma unroll
        for (int off = 8; off; off >>= 1) ss += __shfl_xor(ss, off, 16);
        if (ch == 0) xout[n] = sigm(ss + b2m);
    }
}

// ===========================================================================
// FALLBACK PATH (R5-style, 58 MB ws) -- only if ws_size < 135.2 MB
// ===========================================================================
__global__ void build_rank_fb(const int* __restrict__ ei,
                              int* __restrict__ cnt_i,
                              int* __restrict__ rank)
{
    int e = blockIdx.x * 256 + threadIdx.x;
    rank[e] = atomicAdd(cnt_i + ei[NE + e], 1);
}

template<int DIN>
__global__ __launch_bounds__(256) void edge_compute_fb(
        const int*   __restrict__ ei,
        const float* __restrict__ ea,
        const float* __restrict__ eW1,
        const float* __restrict__ eb1,
        const float* __restrict__ eW2,
        const float* __restrict__ eb2,
        const float* __restrict__ xin,
        const int*   __restrict__ offset,
        const int*   __restrict__ rank,
        float*       __restrict__ msgbuf)
{
    __shared__ __align__(16) float w1[64];
    __shared__ __align__(16) float b1[16];
    __shared__ __align__(16) float w2[16 * DIN * 16];
    __shared__ __align__(16) float b2[DIN * 16];
    int tid = threadIdx.x;
    if (tid < 64) w1[tid] = eW1[tid];
    if (tid < 16) b1[tid] = eb1[tid];
    for (int i = tid; i < 16 * DIN * 16; i += 256) w2[i] = eW2[i];
    for (int i = tid; i < DIN * 16; i += 256) b2[i] = eb2[i];
    __syncthreads();

    int e = blockIdx.x * 256 + tid;
    int src = ei[e];
    int dst = ei[NE + e];
    int pos = offset[dst] + rank[e];
    float4 a = ((const float4*)ea)[e];

    float h[16];
#pragma unroll
    for (int j = 0; j < 16; ++j) {
        float p = b1[j] + a.x * w1[j] + a.y * w1[16 + j] + a.z * w1[32 + j] + a.w * w1[48 + j];
        h[j] = p * sigm(p);
    }
    float xs[DIN];
#pragma unroll
    for (int i4 = 0; i4 < DIN / 4; ++i4)
        ((float4*)xs)[i4] = ((const float4*)(xin + (size_t)src * DIN))[i4];

    float4* mrow = (float4*)(msgbuf + (size_t)pos * 16);
#pragma unroll 1
    for (int ob = 0; ob < 4; ++ob) {
        float4 acc = make_float4(0.f, 0.f, 0.f, 0.f);
#pragma unroll
        for (int i = 0; i < DIN; ++i) {
            float4 w = *((const float4*)(b2 + i * 16) + ob);
#pragma unroll
            for (int k = 0; k < 16; ++k) {
                float4 g = *((const float4*)(w2 + (k * DIN + i) * 16) + ob);
                w.x += h[k] * g.x; w.y += h[k] * g.y;
                w.z += h[k] * g.z; w.w += h[k] * g.w;
            }
            acc.x += xs[i] * w.x; acc.y += xs[i] * w.y;
            acc.z += xs[i] * w.z; acc.w += xs[i] * w.w;
        }
        mrow[ob] = acc;
    }
}

// ===========================================================================
// Host launch
// ===========================================================================
extern "C" void kernel_launch(void* const* d_in, const int* in_sizes, int n_in,
                              void* d_out, int out_size, void* d_ws, size_t ws_size,
                              hipStream_t stream) {
    const float* x     = (const float*)d_in[0];
    const int*   ei    = (const int*)  d_in[1];
    const float* ea    = (const float*)d_in[2];
    const float* eW1_0 = (const float*)d_in[3];
    const float* eb1_0 = (const float*)d_in[4];
    const float* eW2_0 = (const float*)d_in[5];
    const float* eb2_0 = (const float*)d_in[6];
    const float* root0 = (const float*)d_in[7];
    const float* bias0 = (const float*)d_in[8];
    const float* eW1_1 = (const float*)d_in[9];
    const float* eb1_1 = (const float*)d_in[10];
    const float* eW2_1 = (const float*)d_in[11];
    const float* eb2_1 = (const float*)d_in[12];
    const float* root1 = (const float*)d_in[13];
    const float* bias1 = (const float*)d_in[14];
    const float* mW1   = (const float*)d_in[15];
    const float* mb1   = (const float*)d_in[16];
    const float* mW2   = (const float*)d_in[17];
    const float* mb2   = (const float*)d_in[18];
    float* out = (float*)d_out;

    const int EG = NE / 256;          // 3125
    const int GG = NN / 16;           // 3125
    const int PG = (NN + 255) / 256;  // 196

    // ---- new-path ws layout (4B words) ----
    int*   W       = (int*)d_ws;
    int*   cnt_all = W;                     // [0, 100000): cnt_d | cnt_s
    int*   off_all = W + 100000;            // [100000, 200002)
    int*   bsum    = W + 200004;            // [200004, 200516)
    int*   rank_s  = W + 200516;            // NE
    int*   rank_d  = W + 1000516;           // NE
    unsigned long long* pack = (unsigned long long*)(W + 1800516); // NE u64 (8B-aligned)
    float* x1      = (float*)(W + 3400516); // [NN][16]
    float* ea_s    = (float*)(W + 4200516); // [NE][4]
    float* xbuf    = (float*)(W + 7400516); // float4 [4][NN]
    float* G       = (float*)(W + 8200516); // float4 [64][NN]
    float* msgbuf  = (float*)(W + 21000516);// [NE][16]
    const size_t needNew = (size_t)33800516 * 4;  // 135.2 MB

    if (ws_size >= needNew) {
        const int SN = 2 * NN;                       // combined scan length
        const int SB = (SN + 256) / 256;             // 391 (covers offset[SN])
        const int RB = (NE + 1023) / 1024;           // 782 (4 edges/thread)
        hipMemsetAsync(cnt_all, 0, SN * sizeof(int), stream);
        build_ranks<<<RB, 256, 0, stream>>>(ei, cnt_all, cnt_all + NN, rank_s, rank_d);
        scan_k1<<<SB, 256, 0, stream>>>(cnt_all, SN, bsum);
        scan_k2<<<1, 512, 0, stream>>>(bsum, SB);
        scan_k3<<<SB, 256, 0, stream>>>(cnt_all, SN, bsum, off_all);
        build_perm<<<EG, 256, 0, stream>>>(ei, ea, off_all, rank_s, rank_d,
                                           pack, ea_s);
        // ---- layer 0 ----
        precompute_G<8><<<PG, 256, 0, stream>>>(x, eW2_0, eb2_0, G, xbuf);
        edge_msg<<<EG, 256, 0, stream>>>(pack, ea_s, eW1_0, eb1_0, G, xbuf, msgbuf);
        gather_nodes<8, false><<<GG, 256, 0, stream>>>(x, root0, bias0, off_all, msgbuf,
                                                       mW1, mb1, mW2, mb2, x1);
        // ---- layer 1 ----
        precompute_G<16><<<PG, 256, 0, stream>>>(x1, eW2_1, eb2_1, G, xbuf);
        edge_msg<<<EG, 256, 0, stream>>>(pack, ea_s, eW1_1, eb1_1, G, xbuf, msgbuf);
        gather_nodes<16, true><<<GG, 256, 0, stream>>>(x1, root1, bias1, off_all, msgbuf,
                                                       mW1, mb1, mW2, mb2, out);
    } else {
        // ---- fallback (58 MB): R5 structure with fast scan ----
        int*   cnt_i  = (int*)d_ws;                 // NN
        int*   offset = cnt_i + NN;                 // NN+1
        int*   bsumF  = (int*)d_ws + 100004;        // 512
        int*   rank   = (int*)d_ws + 100516;        // NE
        float* msgb   = (float*)d_ws + 900516;      // [NE][16]
        float* x1f    = (float*)d_ws + 13700516;    // [NN][16]
        const int FB = (NN + 1 + 255) / 256;        // 196

        hipMemsetAsync(cnt_i, 0, NN * sizeof(int), stream);
        build_rank_fb<<<EG, 256, 0, stream>>>(ei, cnt_i, rank);
        scan_k1<<<FB, 256, 0, stream>>>(cnt_i, NN, bsumF);
        scan_k2<<<1, 512, 0, stream>>>(bsumF, FB);
        scan_k3<<<FB, 256, 0, stream>>>(cnt_i, NN, bsumF, offset);
        edge_compute_fb<8><<<EG, 256, 0, stream>>>(ei, ea, eW1_0, eb1_0, eW2_0, eb2_0,
                                                   x, offset, rank, msgb);
        gather_nodes<8, false><<<GG, 256, 0, stream>>>(x, root0, bias0, offset, msgb,
                                                       mW1, mb1, mW2, mb2, x1f);
        edge_compute_fb<16><<<EG, 256, 0, stream>>>(ei, ea, eW1_1, eb1_1, eW2_1, eb2_1,
                                                    x1f, offset, rank, msgb);
        gather_nodes<16, true><<<GG, 256, 0, stream>>>(x1f, root1, bias1, offset, msgb,
                                                       mW1, mb1, mW2, mb2, out);
    }
}